// Round 1
// baseline (93.801 us; speedup 1.0000x reference)
//
#include <hip/hip_runtime.h>
#include <hip/hip_bf16.h>

#define NB 256
#define NK 32
#define NL 4096
#define EPSV 1e-5f
#define PEAK_LAMBDA 0.005f
#define ORTHO_LAMBDA 20000.0f

typedef __attribute__((ext_vector_type(8))) short short8;
typedef __attribute__((ext_vector_type(4))) float f32x4;

static __device__ inline unsigned short f2bf(float f) {
    // round-to-nearest-even fp32 -> bf16 (inputs are positive normals)
    unsigned int u = __float_as_uint(f);
    unsigned int r = (u + 0x7fffu + ((u >> 16) & 1u)) >> 16;
    return (unsigned short)r;
}

// ---------------- Kernel 1: per-row argmax + Z + KL ----------------
// grid = 8192 (one block per (b,k) row), block = 256. Each thread holds its
// 16 elements in registers so only ONE global pass is needed.
__global__ __launch_bounds__(256) void k_rows(const float* __restrict__ a,
                                              float* __restrict__ row_kl) {
    const int row = blockIdx.x;
    const int tid = threadIdx.x;
    const float4* __restrict__ ar4 =
        reinterpret_cast<const float4*>(a + (size_t)row * NL);

    float4 v[4];
#pragma unroll
    for (int j = 0; j < 4; ++j) v[j] = ar4[tid + 256 * j];

    // local argmax, scanning in increasing-l order (strict > => first occurrence)
    float bv = -1.0f;
    int bl = 0;
#pragma unroll
    for (int j = 0; j < 4; ++j) {
        const float* pv = reinterpret_cast<const float*>(&v[j]);
        const int lbase = (tid + 256 * j) * 4;
#pragma unroll
        for (int c = 0; c < 4; ++c) {
            float val = pv[c];
            if (val > bv) { bv = val; bl = lbase + c; }
        }
    }

    __shared__ float sv[256];
    __shared__ int si[256];
    sv[tid] = bv;
    si[tid] = bl;
    __syncthreads();
    for (int s = 128; s > 0; s >>= 1) {
        if (tid < s) {
            float ov = sv[tid + s]; int oi = si[tid + s];
            float cv = sv[tid];     int ci = si[tid];
            if (ov > cv || (ov == cv && oi < ci)) { sv[tid] = ov; si[tid] = oi; }
        }
        __syncthreads();
    }
    const int idx = si[0];
    __syncthreads();  // done with sv/si contents before reuse

    // Z = sum_l exp(-0.5*((l-idx)/sigma)^2), keep per-element g in registers
    float g[16];
    float zs = 0.0f;
#pragma unroll
    for (int j = 0; j < 4; ++j) {
        const int lbase = (tid + 256 * j) * 4;
#pragma unroll
        for (int c = 0; c < 4; ++c) {
            float d = (float)(lbase + c - idx) * (1.0f / 1.5f);
            float e = __expf(-0.5f * d * d);
            g[j * 4 + c] = e;
            zs += e;
        }
    }
    sv[tid] = zs;
    __syncthreads();
    for (int s = 128; s > 0; s >>= 1) {
        if (tid < s) sv[tid] += sv[tid + s];
        __syncthreads();
    }
    const float rz = 1.0f / sv[0];
    __syncthreads();

    // KL partial: sum t*(log t - log p)
    float acc = 0.0f;
#pragma unroll
    for (int j = 0; j < 4; ++j) {
        const float* pv = reinterpret_cast<const float*>(&v[j]);
#pragma unroll
        for (int c = 0; c < 4; ++c) {
            float p = pv[c] + EPSV;
            float t = g[j * 4 + c] * rz + EPSV;
            acc += t * (__logf(t) - __logf(p));
        }
    }
    sv[tid] = acc;
    __syncthreads();
    for (int s = 128; s > 0; s >>= 1) {
        if (tid < s) sv[tid] += sv[tid + s];
        __syncthreads();
    }
    if (tid == 0) row_kl[row] = sv[0];
}

// ---------------- Kernel 2: per-b Gram matrix via bf16 MFMA ----------------
// grid = 256 (one block per b), block = 256 (4 waves). L is tiled by 512;
// all 4 waves stage one tile cooperatively (fp32 -> bf16, +eps, XOR-swizzled
// LDS), then each wave MFMAs its quarter of the tile's l-range into a partial
// 32x32 Gram held in 4 accumulator tiles. Cross-wave reduce + off-diag^2 sum.
__global__ __launch_bounds__(256) void k_gram(const float* __restrict__ a,
                                              float* __restrict__ ortho_b) {
    const int b = blockIdx.x;
    const int tid = threadIdx.x;
    const int lane = tid & 63;
    const int wv = tid >> 6;

    __shared__ unsigned short tile[NK * 512];  // bf16 bits, swizzled (32 KiB)
    __shared__ float gbuf[4 * NK * NK];        // per-wave partial G (16 KiB)
    __shared__ float red[256];

    const float* __restrict__ ab = a + (size_t)b * NK * NL;
    char* tb = reinterpret_cast<char*>(tile);

    f32x4 acc00 = {0.f, 0.f, 0.f, 0.f};
    f32x4 acc01 = {0.f, 0.f, 0.f, 0.f};
    f32x4 acc10 = {0.f, 0.f, 0.f, 0.f};
    f32x4 acc11 = {0.f, 0.f, 0.f, 0.f};

    for (int t = 0; t < NL / 512; ++t) {
        __syncthreads();
        // stage 32x512 fp32 -> bf16 (+eps), XOR swizzle byte^((row&7)<<4)
#pragma unroll
        for (int j = 0; j < 16; ++j) {
            int fi = tid + 256 * j;     // float4 index within tile (0..4095)
            int row = fi >> 7;          // 128 float4 per row
            int c4 = fi & 127;
            float4 vv = reinterpret_cast<const float4*>(
                ab + (size_t)row * NL + t * 512)[c4];
            uint2 pk;
            pk.x = (unsigned int)f2bf(vv.x + EPSV) |
                   ((unsigned int)f2bf(vv.y + EPSV) << 16);
            pk.y = (unsigned int)f2bf(vv.z + EPSV) |
                   ((unsigned int)f2bf(vv.w + EPSV) << 16);
            int byte = row * 1024 + c4 * 8;
            byte ^= (row & 7) << 4;
            *reinterpret_cast<uint2*>(tb + byte) = pk;
        }
        __syncthreads();
        // compute: wave wv owns l in [wv*128, wv*128+128) of this tile
#pragma unroll
        for (int s = 0; s < 4; ++s) {
            int l0 = wv * 128 + s * 32;
            int r0 = lane & 15;
            int elem = l0 + (lane >> 4) * 8;
            int byteA = r0 * 1024 + elem * 2;
            byteA ^= (r0 & 7) << 4;
            int r1 = 16 + r0;
            int byteB = r1 * 1024 + elem * 2;
            byteB ^= (r1 & 7) << 4;
            short8 f0 = *reinterpret_cast<const short8*>(tb + byteA);
            short8 f1 = *reinterpret_cast<const short8*>(tb + byteB);
            acc00 = __builtin_amdgcn_mfma_f32_16x16x32_bf16(f0, f0, acc00, 0, 0, 0);
            acc01 = __builtin_amdgcn_mfma_f32_16x16x32_bf16(f0, f1, acc01, 0, 0, 0);
            acc10 = __builtin_amdgcn_mfma_f32_16x16x32_bf16(f1, f0, acc10, 0, 0, 0);
            acc11 = __builtin_amdgcn_mfma_f32_16x16x32_bf16(f1, f1, acc11, 0, 0, 0);
        }
    }

    __syncthreads();
    // write per-wave partial G. C/D layout (m89-verified): col=lane&15,
    // row=(lane>>4)*4+reg
    {
        int col = lane & 15;
        int rbase = (lane >> 4) * 4;
#pragma unroll
        for (int r = 0; r < 4; ++r) {
            int gr = rbase + r;
            gbuf[wv * 1024 + gr * 32 + col]             = acc00[r];
            gbuf[wv * 1024 + gr * 32 + 16 + col]        = acc01[r];
            gbuf[wv * 1024 + (16 + gr) * 32 + col]      = acc10[r];
            gbuf[wv * 1024 + (16 + gr) * 32 + 16 + col] = acc11[r];
        }
    }
    __syncthreads();

    // reduce 4 waves, accumulate off-diagonal squares
    float local = 0.0f;
#pragma unroll
    for (int e4 = 0; e4 < 4; ++e4) {
        int e = tid * 4 + e4;
        float s = gbuf[e] + gbuf[1024 + e] + gbuf[2048 + e] + gbuf[3072 + e];
        int k = e >> 5, m = e & 31;
        if (k != m) local += s * s;
    }
    red[tid] = local;
    __syncthreads();
    for (int s = 128; s > 0; s >>= 1) {
        if (tid < s) red[tid] += red[tid + s];
        __syncthreads();
    }
    if (tid == 0) ortho_b[b] = red[0];
}

// ---------------- Kernel 3: final reduction ----------------
__global__ __launch_bounds__(256) void k_final(const float* __restrict__ row_kl,
                                               const float* __restrict__ ortho_b,
                                               float* __restrict__ out) {
    const int tid = threadIdx.x;
    __shared__ float s1[256], s2[256];
    float akl = 0.0f;
    for (int j = tid; j < NB * NK; j += 256) akl += row_kl[j];
    s1[tid] = akl;
    s2[tid] = ortho_b[tid];  // NB == 256
    __syncthreads();
    for (int s = 128; s > 0; s >>= 1) {
        if (tid < s) { s1[tid] += s1[tid + s]; s2[tid] += s2[tid + s]; }
        __syncthreads();
    }
    if (tid == 0) {
        float peak = PEAK_LAMBDA * s1[0];
        float ortho = ORTHO_LAMBDA * (s2[0] / (float)(NB * NK * NK));
        out[0] = peak + ortho;
        out[1] = peak;
        out[2] = ortho;
    }
}

extern "C" void kernel_launch(void* const* d_in, const int* in_sizes, int n_in,
                              void* d_out, int out_size, void* d_ws, size_t ws_size,
                              hipStream_t stream) {
    const float* a = (const float*)d_in[0];
    float* out = (float*)d_out;
    float* row_kl = (float*)d_ws;          // 8192 floats
    float* ortho_b = row_kl + NB * NK;     // 256 floats

    k_rows<<<NB * NK, 256, 0, stream>>>(a, row_kl);
    k_gram<<<NB, 256, 0, stream>>>(a, ortho_b);
    k_final<<<1, 256, 0, stream>>>(row_kl, ortho_b, out);
}

// Round 2
// 64.311 us; speedup vs baseline: 1.4586x; 1.4586x over previous
//
#include <hip/hip_runtime.h>
#include <hip/hip_bf16.h>

#define NB 256
#define NK 32
#define NL 4096
#define NC 4            // L-chunks per row
#define CHLEN 1024      // chunk length
#define TL 512          // LDS tile length
#define EPSV 1e-5f
#define PEAK_LAMBDA 0.005f
#define ORTHO_LAMBDA 20000.0f

typedef __attribute__((ext_vector_type(8))) short short8;
typedef __attribute__((ext_vector_type(4))) float f32x4;

static __device__ inline unsigned short f2bf(float f) {
    // round-to-nearest-even fp32 -> bf16 (inputs are positive normals)
    unsigned int u = __float_as_uint(f);
    unsigned int r = (u + 0x7fffu + ((u >> 16) & 1u)) >> 16;
    return (unsigned short)r;
}

// ---------------- Kernel 1: fused single-pass ----------------
// grid = NB*NC (b-major), block = 512 (8 waves). Each block handles a 32x1024
// chunk of one b: streams it ONCE from HBM, producing (a) per-row argmax
// partials, (b) per-row sum(log(a+eps)) partials, (c) bf16-MFMA Gram partial.
__global__ __launch_bounds__(512) void k_main(const float* __restrict__ a,
                                              float* __restrict__ gram,
                                              float* __restrict__ rmax,
                                              int* __restrict__ ridx,
                                              float* __restrict__ rlogp) {
    const int bc = blockIdx.x;
    const int b = bc >> 2;
    const int chk = bc & 3;
    const int tid = threadIdx.x;
    const int lane = tid & 63;
    const int wv = tid >> 6;
    const int q = tid >> 7;      // 0..3
    const int c = tid & 127;     // float4 column within row

    __shared__ float smf[8192];          // 32 KiB, multi-purpose
    int* smi = (int*)smf;
    char* tb = (char*)smf;

    const float* __restrict__ ab = a + (size_t)b * NK * NL + chk * CHLEN;

    // per-thread per-row partials; row = 4*j + q (fixed per thread)
    float mval[8];
    int midx[8];
    float lps[8];
#pragma unroll
    for (int j = 0; j < 8; ++j) { mval[j] = -1.0f; midx[j] = 0; lps[j] = 0.0f; }
    f32x4 acc00 = {0.f,0.f,0.f,0.f}, acc01 = {0.f,0.f,0.f,0.f};
    f32x4 acc10 = {0.f,0.f,0.f,0.f}, acc11 = {0.f,0.f,0.f,0.f};

    for (int t = 0; t < 2; ++t) {
        __syncthreads();
        // stage 32x512 fp32 -> bf16(+eps) swizzled LDS; fuse argmax + logp
#pragma unroll
        for (int j = 0; j < 8; ++j) {
            const int row = 4 * j + q;
            float4 vv = reinterpret_cast<const float4*>(
                ab + (size_t)row * NL + t * TL)[c];
            const int lbase = chk * CHLEN + t * TL + c * 4;
            const float* pv = reinterpret_cast<const float*>(&vv);
#pragma unroll
            for (int cc = 0; cc < 4; ++cc) {
                float val = pv[cc];
                if (val > mval[j]) { mval[j] = val; midx[j] = lbase + cc; }
                lps[j] += __logf(val + EPSV);
            }
            uint2 pk;
            pk.x = (unsigned)f2bf(vv.x + EPSV) | ((unsigned)f2bf(vv.y + EPSV) << 16);
            pk.y = (unsigned)f2bf(vv.z + EPSV) | ((unsigned)f2bf(vv.w + EPSV) << 16);
            int byte = row * 1024 + c * 8;
            byte ^= (row & 7) << 4;
            *reinterpret_cast<uint2*>(tb + byte) = pk;
        }
        __syncthreads();
        // Gram MFMA: wave wv owns l in [wv*64, wv*64+64) of this 512-tile
#pragma unroll
        for (int s = 0; s < 2; ++s) {
            const int l0 = wv * 64 + s * 32;
            const int r0 = lane & 15;
            const int elem = l0 + (lane >> 4) * 8;
            int byteA = r0 * 1024 + elem * 2;        byteA ^= (r0 & 7) << 4;
            int byteB = (16 + r0) * 1024 + elem * 2; byteB ^= (r0 & 7) << 4;
            short8 f0 = *reinterpret_cast<const short8*>(tb + byteA);
            short8 f1 = *reinterpret_cast<const short8*>(tb + byteB);
            acc00 = __builtin_amdgcn_mfma_f32_16x16x32_bf16(f0, f0, acc00, 0, 0, 0);
            acc01 = __builtin_amdgcn_mfma_f32_16x16x32_bf16(f0, f1, acc01, 0, 0, 0);
            acc10 = __builtin_amdgcn_mfma_f32_16x16x32_bf16(f1, f0, acc10, 0, 0, 0);
            acc11 = __builtin_amdgcn_mfma_f32_16x16x32_bf16(f1, f1, acc11, 0, 0, 0);
        }
    }
    __syncthreads();

    // ---- argmax cross-thread reduce (row r owned by 128 threads) ----
#pragma unroll
    for (int j = 0; j < 8; ++j) {
        smf[j * 512 + tid] = mval[j];
        smi[4096 + j * 512 + tid] = midx[j];
    }
    __syncthreads();
    for (int s = 64; s > 0; s >>= 1) {
        if (c < s) {
#pragma unroll
            for (int j = 0; j < 8; ++j) {
                int i0 = j * 512 + q * 128 + c, i1 = i0 + s;
                float ov = smf[i1]; int oi = smi[4096 + i1];
                float cv = smf[i0]; int ci = smi[4096 + i0];
                if (ov > cv || (ov == cv && oi < ci)) { smf[i0] = ov; smi[4096 + i0] = oi; }
            }
        }
        __syncthreads();
    }
    if (tid < 32) {
        int i0 = (tid >> 2) * 512 + (tid & 3) * 128;
        rmax[bc * 32 + tid] = smf[i0];
        ridx[bc * 32 + tid] = smi[4096 + i0];
    }
    __syncthreads();

    // ---- logp cross-thread reduce ----
#pragma unroll
    for (int j = 0; j < 8; ++j) smf[j * 512 + tid] = lps[j];
    __syncthreads();
    for (int s = 64; s > 0; s >>= 1) {
        if (c < s) {
#pragma unroll
            for (int j = 0; j < 8; ++j) {
                int i0 = j * 512 + q * 128 + c;
                smf[i0] += smf[i0 + s];
            }
        }
        __syncthreads();
    }
    if (tid < 32) rlogp[bc * 32 + tid] = smf[(tid >> 2) * 512 + (tid & 3) * 128];
    __syncthreads();

    // ---- Gram cross-wave reduce; C/D layout: col=lane&15, row=(lane>>4)*4+reg
    {
        int col = lane & 15, rb = (lane >> 4) * 4;
#pragma unroll
        for (int r = 0; r < 4; ++r) {
            int gr = rb + r;
            smf[wv * 1024 + gr * 32 + col]              = acc00[r];
            smf[wv * 1024 + gr * 32 + 16 + col]         = acc01[r];
            smf[wv * 1024 + (16 + gr) * 32 + col]       = acc10[r];
            smf[wv * 1024 + (16 + gr) * 32 + 16 + col]  = acc11[r];
        }
    }
    __syncthreads();
#pragma unroll
    for (int e4 = 0; e4 < 2; ++e4) {
        int e = tid + 512 * e4;
        float ssum = 0.0f;
#pragma unroll
        for (int w = 0; w < 8; ++w) ssum += smf[w * 1024 + e];
        gram[(size_t)bc * 1024 + e] = ssum;
    }
}

// ---------------- Kernel 2: per-b finalize ----------------
// grid = NB, block = 256. Combines chunk partials; computes the exact KL via
// the 64-wide Gaussian window (g==0 outside |d|<=21 in fp32); off-diag Gram^2.
__global__ __launch_bounds__(256) void k_fin(const float* __restrict__ a,
                                             const float* __restrict__ gram,
                                             const float* __restrict__ rmax,
                                             const int* __restrict__ ridx,
                                             const float* __restrict__ rlogp,
                                             float* __restrict__ bpeak,
                                             float* __restrict__ bortho) {
    const int b = blockIdx.x;
    const int tid = threadIdx.x;
    __shared__ int idx_s[32];
    __shared__ float lp_s[32];
    __shared__ float rkl_s[32];
    __shared__ float red[256];

    // ortho: sum 4 chunk Grams, off-diagonal squares
    float local = 0.0f;
#pragma unroll
    for (int e4 = 0; e4 < 4; ++e4) {
        int e = tid + 256 * e4;
        float s = gram[(size_t)(b * 4 + 0) * 1024 + e]
                + gram[(size_t)(b * 4 + 1) * 1024 + e]
                + gram[(size_t)(b * 4 + 2) * 1024 + e]
                + gram[(size_t)(b * 4 + 3) * 1024 + e];
        int k = e >> 5, m = e & 31;
        if (k != m) local += s * s;
    }

    // combine per-row chunk partials (chunks are ascending-l; idx tiebreak)
    if (tid < 32) {
        float bv = -1.0f; int bi = 0; float lp = 0.0f;
#pragma unroll
        for (int ch = 0; ch < 4; ++ch) {
            float v = rmax[(b * 4 + ch) * 32 + tid];
            int i = ridx[(b * 4 + ch) * 32 + tid];
            if (v > bv || (v == bv && i < bi)) { bv = v; bi = i; }
            lp += rlogp[(b * 4 + ch) * 32 + tid];
        }
        idx_s[tid] = bi; lp_s[tid] = lp;
    }
    __syncthreads();

    // window: 8 threads per row, 8 positions each, l = idx-31 .. idx+32
    const int r = tid >> 3, cc = tid & 7;
    const int idx = idx_s[r];
    const float* __restrict__ arow = a + ((size_t)b * 32 + r) * (size_t)NL;
    float gv[8], pvv[8];
    float zs = 0.0f;
#pragma unroll
    for (int w = 0; w < 8; ++w) {
        int l = idx - 31 + cc + 8 * w;
        float d = (float)(cc + 8 * w - 31);
        float g = __expf(d * d * (-1.0f / 4.5f));
        if (l >= 0 && l < NL) { gv[w] = g; zs += g; pvv[w] = arow[l]; }
        else { gv[w] = 0.0f; pvv[w] = 1.0f; }
    }
    zs += __shfl_xor(zs, 1); zs += __shfl_xor(zs, 2); zs += __shfl_xor(zs, 4);
    const float rz = 1.0f / zs;
    float tlt = 0.0f, tlp = 0.0f;
#pragma unroll
    for (int w = 0; w < 8; ++w) {
        int l = idx - 31 + cc + 8 * w;
        if (l >= 0 && l < NL) {
            float gg = gv[w] * rz;
            float tf = gg + EPSV;
            tlt += tf * __logf(tf);
            tlp += gg * __logf(pvv[w] + EPSV);
        }
    }
    tlt += __shfl_xor(tlt, 1); tlt += __shfl_xor(tlt, 2); tlt += __shfl_xor(tlt, 4);
    tlp += __shfl_xor(tlp, 1); tlp += __shfl_xor(tlp, 2); tlp += __shfl_xor(tlp, 4);
    if (cc == 0) {
        int lo = max(0, idx - 31), hi = min(NL - 1, idx + 32);
        int nv = hi - lo + 1;
        rkl_s[r] = tlt + (float)(NL - nv) * EPSV * __logf(EPSV)
                 - tlp - EPSV * lp_s[r];
    }
    red[tid] = local;
    __syncthreads();
    for (int s = 128; s > 0; s >>= 1) {
        if (tid < s) red[tid] += red[tid + s];
        __syncthreads();
    }
    if (tid == 0) bortho[b] = red[0];
    __syncthreads();
    red[tid] = (tid < 32) ? rkl_s[tid] : 0.0f;
    __syncthreads();
    for (int s = 128; s > 0; s >>= 1) {
        if (tid < s) red[tid] += red[tid + s];
        __syncthreads();
    }
    if (tid == 0) bpeak[b] = red[0];
}

// ---------------- Kernel 3: final 256 -> scalars ----------------
__global__ __launch_bounds__(256) void k_final(const float* __restrict__ bpeak,
                                               const float* __restrict__ bortho,
                                               float* __restrict__ out) {
    const int tid = threadIdx.x;
    __shared__ float s1[256], s2[256];
    s1[tid] = bpeak[tid];
    s2[tid] = bortho[tid];
    __syncthreads();
    for (int s = 128; s > 0; s >>= 1) {
        if (tid < s) { s1[tid] += s1[tid + s]; s2[tid] += s2[tid + s]; }
        __syncthreads();
    }
    if (tid == 0) {
        float peak = PEAK_LAMBDA * s1[0];
        float ortho = ORTHO_LAMBDA * (s2[0] / (float)(NB * NK * NK));
        out[0] = peak + ortho;
        out[1] = peak;
        out[2] = ortho;
    }
}

extern "C" void kernel_launch(void* const* d_in, const int* in_sizes, int n_in,
                              void* d_out, int out_size, void* d_ws, size_t ws_size,
                              hipStream_t stream) {
    const float* a = (const float*)d_in[0];
    float* out = (float*)d_out;
    float* ws = (float*)d_ws;
    float* gram  = ws;                       // NB*NC*1024 = 1,048,576 floats
    float* rmax  = gram + (size_t)NB * NC * 1024;   // 32768
    int*   ridxp = (int*)(rmax + NB * NC * 32);     // 32768
    float* rlogp = (float*)(ridxp + NB * NC * 32);  // 32768
    float* bpeak = rlogp + NB * NC * 32;            // 256
    float* bortho = bpeak + NB;                     // 256

    k_main<<<NB * NC, 512, 0, stream>>>(a, gram, rmax, ridxp, rlogp);
    k_fin<<<NB, 256, 0, stream>>>(a, gram, rmax, ridxp, rlogp, bpeak, bortho);
    k_final<<<1, 256, 0, stream>>>(bpeak, bortho, out);
}

// Round 3
// 49.824 us; speedup vs baseline: 1.8827x; 1.2908x over previous
//
#include <hip/hip_runtime.h>
#include <hip/hip_bf16.h>

#define NB 256
#define NK 32
#define NL 4096
#define NC 4            // L-chunks per row
#define CH 1024         // chunk length
#define EPSV 1e-5f
#define PEAK_LAMBDA 0.005f
#define ORTHO_LAMBDA 20000.0f

typedef __attribute__((ext_vector_type(8))) short short8;
typedef __attribute__((ext_vector_type(4))) float f32x4;

static __device__ inline unsigned f2bf(float f) {
    // round-to-nearest-even fp32 -> bf16 (inputs are positive normals)
    unsigned u = __float_as_uint(f);
    return (u + 0x7fffu + ((u >> 16) & 1u)) >> 16;
}

// ---------------- Kernel 1: fused single-pass, no LDS staging ----------------
// grid = NB*NC (b-major), block = 256 (4 waves). Each block covers a 32x1024
// chunk of one b. Each lane loads its MFMA fragments (rows lane&15 and
// 16+(lane&15), 8 consecutive floats at hi*8) DIRECTLY from global, converts
// to bf16 in registers, and fuses argmax + sum(log(a+eps)) on the same data.
// Main loop: 0 barriers, 0 LDS. Gram uses symmetry: acc10 == acc01^T skipped.
__global__ __launch_bounds__(256) void k_main(const float* __restrict__ a,
                                              float* __restrict__ gram,
                                              float* __restrict__ rmax,
                                              int* __restrict__ ridx,
                                              float* __restrict__ rlogp) {
    const int bc = blockIdx.x;
    const int b = bc >> 2, chk = bc & 3;
    const int tid = threadIdx.x;
    const int lane = tid & 63, wv = tid >> 6;
    const int r0 = lane & 15, hi = lane >> 4;

    // wave wv owns l in [wv*256, wv*256+256) of the chunk: 8 MFMA k-steps
    const float* __restrict__ rowA =
        a + ((size_t)b * NK + r0) * NL + chk * CH + wv * 256 + hi * 8;
    const float* __restrict__ rowB = rowA + 16 * (size_t)NL;
    const int lbase = chk * CH + wv * 256 + hi * 8;

    float mvA = -1.0f, mvB = -1.0f, lpA = 0.0f, lpB = 0.0f;
    int miA = 0, miB = 0;
    f32x4 acc00 = {0.f,0.f,0.f,0.f}, acc01 = {0.f,0.f,0.f,0.f},
          acc11 = {0.f,0.f,0.f,0.f};

#pragma unroll
    for (int s = 0; s < 8; ++s) {
        float4 a0 = *reinterpret_cast<const float4*>(rowA + s * 32);
        float4 a1 = *reinterpret_cast<const float4*>(rowA + s * 32 + 4);
        float4 b0 = *reinterpret_cast<const float4*>(rowB + s * 32);
        float4 b1 = *reinterpret_cast<const float4*>(rowB + s * 32 + 4);
        float va[8] = {a0.x, a0.y, a0.z, a0.w, a1.x, a1.y, a1.z, a1.w};
        float vb[8] = {b0.x, b0.y, b0.z, b0.w, b1.x, b1.y, b1.z, b1.w};
        const int l0 = lbase + s * 32;
#pragma unroll
        for (int c = 0; c < 8; ++c) {
            float v = va[c];
            if (v > mvA) { mvA = v; miA = l0 + c; }
            lpA += __logf(v + EPSV);
            float w = vb[c];
            if (w > mvB) { mvB = w; miB = l0 + c; }
            lpB += __logf(w + EPSV);
        }
        union { unsigned u[4]; short8 s8; } fa, fb;
#pragma unroll
        for (int c = 0; c < 4; ++c) {
            fa.u[c] = f2bf(va[2*c] + EPSV) | (f2bf(va[2*c+1] + EPSV) << 16);
            fb.u[c] = f2bf(vb[2*c] + EPSV) | (f2bf(vb[2*c+1] + EPSV) << 16);
        }
        acc00 = __builtin_amdgcn_mfma_f32_16x16x32_bf16(fa.s8, fa.s8, acc00, 0, 0, 0);
        acc01 = __builtin_amdgcn_mfma_f32_16x16x32_bf16(fa.s8, fb.s8, acc01, 0, 0, 0);
        acc11 = __builtin_amdgcn_mfma_f32_16x16x32_bf16(fb.s8, fb.s8, acc11, 0, 0, 0);
    }

    // ---- cross-lane per-row reduce: row r0 lives in lanes {r0,+16,+32,+48}
#pragma unroll
    for (int off = 16; off <= 32; off <<= 1) {
        float ov = __shfl_xor(mvA, off); int oi = __shfl_xor(miA, off);
        if (ov > mvA || (ov == mvA && oi < miA)) { mvA = ov; miA = oi; }
        ov = __shfl_xor(mvB, off); oi = __shfl_xor(miB, off);
        if (ov > mvB || (ov == mvB && oi < miB)) { mvB = ov; miB = oi; }
        lpA += __shfl_xor(lpA, off);
        lpB += __shfl_xor(lpB, off);
    }

    __shared__ float s_mv[4][32], s_lp[4][32];
    __shared__ int   s_mi[4][32];
    __shared__ float gbuf[4][768];

    if (hi == 0) {
        s_mv[wv][r0] = mvA; s_mi[wv][r0] = miA; s_lp[wv][r0] = lpA;
        s_mv[wv][16 + r0] = mvB; s_mi[wv][16 + r0] = miB; s_lp[wv][16 + r0] = lpB;
    }
    // Gram C/D layout (m89-verified): col = lane&15, row = (lane>>4)*4 + reg
    {
        const int rb2 = hi * 4;
#pragma unroll
        for (int r = 0; r < 4; ++r) {
            int gr = rb2 + r;
            gbuf[wv][gr * 16 + r0]       = acc00[r];
            gbuf[wv][256 + gr * 16 + r0] = acc01[r];
            gbuf[wv][512 + gr * 16 + r0] = acc11[r];
        }
    }
    __syncthreads();

    if (tid < 32) {  // combine 4 wave partials per row (waves ascending-l)
        float bv = -1.0f, lp = 0.0f; int bi = 0;
#pragma unroll
        for (int w = 0; w < 4; ++w) {
            float v = s_mv[w][tid]; int i = s_mi[w][tid];
            if (v > bv || (v == bv && i < bi)) { bv = v; bi = i; }
            lp += s_lp[w][tid];
        }
        rmax[bc * 32 + tid] = bv;
        ridx[bc * 32 + tid] = bi;
        rlogp[bc * 32 + tid] = lp;
    }
#pragma unroll
    for (int j = 0; j < 3; ++j) {
        int e = tid + 256 * j;
        gram[(size_t)bc * 768 + e] =
            gbuf[0][e] + gbuf[1][e] + gbuf[2][e] + gbuf[3][e];
    }
}

// ---------------- Kernel 2: per-b finalize ----------------
// Combines chunk partials; exact KL via the 64-wide Gaussian window
// (g underflows to 0 for |d|>=22 in fp32); off-diag Gram^2 with G01 weight 2.
__global__ __launch_bounds__(256) void k_fin(const float* __restrict__ a,
                                             const float* __restrict__ gram,
                                             const float* __restrict__ rmax,
                                             const int* __restrict__ ridx,
                                             const float* __restrict__ rlogp,
                                             float* __restrict__ bpeak,
                                             float* __restrict__ bortho) {
    const int b = blockIdx.x;
    const int tid = threadIdx.x;
    __shared__ int idx_s[32];
    __shared__ float lp_s[32];
    __shared__ float rkl_s[32];
    __shared__ float red[256];

    // ortho: sum 4 chunk Grams then square. blocks: [0]=G00 [1]=G01 [2]=G11
    float local = 0.0f;
#pragma unroll
    for (int j = 0; j < 3; ++j) {
        int e = tid + 256 * j;
        float s = gram[(size_t)(b * 4 + 0) * 768 + e]
                + gram[(size_t)(b * 4 + 1) * 768 + e]
                + gram[(size_t)(b * 4 + 2) * 768 + e]
                + gram[(size_t)(b * 4 + 3) * 768 + e];
        int blk = e >> 8, idx = e & 255, k = idx >> 4, m = idx & 15;
        float w = (blk == 1) ? 2.0f : ((k == m) ? 0.0f : 1.0f);
        local += w * s * s;
    }

    // combine per-row chunk partials (chunks ascending-l; idx tiebreak)
    if (tid < 32) {
        float bv = -1.0f; int bi = 0; float lp = 0.0f;
#pragma unroll
        for (int ch = 0; ch < 4; ++ch) {
            float v = rmax[(b * 4 + ch) * 32 + tid];
            int i = ridx[(b * 4 + ch) * 32 + tid];
            if (v > bv || (v == bv && i < bi)) { bv = v; bi = i; }
            lp += rlogp[(b * 4 + ch) * 32 + tid];
        }
        idx_s[tid] = bi; lp_s[tid] = lp;
    }
    __syncthreads();

    // window: 8 threads per row, 8 positions each, l = idx-31 .. idx+32
    const int r = tid >> 3, cc = tid & 7;
    const int idx = idx_s[r];
    const float* __restrict__ arow = a + ((size_t)b * 32 + r) * (size_t)NL;
    float gv[8], pvv[8];
    float zs = 0.0f;
#pragma unroll
    for (int w = 0; w < 8; ++w) {
        int l = idx - 31 + cc + 8 * w;
        float d = (float)(cc + 8 * w - 31);
        float g = __expf(d * d * (-1.0f / 4.5f));
        if (l >= 0 && l < NL) { gv[w] = g; zs += g; pvv[w] = arow[l]; }
        else { gv[w] = 0.0f; pvv[w] = 1.0f; }
    }
    zs += __shfl_xor(zs, 1); zs += __shfl_xor(zs, 2); zs += __shfl_xor(zs, 4);
    const float rz = 1.0f / zs;
    float tlt = 0.0f, tlp = 0.0f;
#pragma unroll
    for (int w = 0; w < 8; ++w) {
        int l = idx - 31 + cc + 8 * w;
        if (l >= 0 && l < NL) {
            float gg = gv[w] * rz;
            float tf = gg + EPSV;
            tlt += tf * __logf(tf);
            tlp += gg * __logf(pvv[w] + EPSV);
        }
    }
    tlt += __shfl_xor(tlt, 1); tlt += __shfl_xor(tlt, 2); tlt += __shfl_xor(tlt, 4);
    tlp += __shfl_xor(tlp, 1); tlp += __shfl_xor(tlp, 2); tlp += __shfl_xor(tlp, 4);
    if (cc == 0) {
        int lo = max(0, idx - 31), hi2 = min(NL - 1, idx + 32);
        int nv = hi2 - lo + 1;
        rkl_s[r] = tlt + (float)(NL - nv) * EPSV * __logf(EPSV)
                 - tlp - EPSV * lp_s[r];
    }
    red[tid] = local;
    __syncthreads();
    for (int s = 128; s > 0; s >>= 1) {
        if (tid < s) red[tid] += red[tid + s];
        __syncthreads();
    }
    if (tid == 0) bortho[b] = red[0];
    __syncthreads();
    red[tid] = (tid < 32) ? rkl_s[tid] : 0.0f;
    __syncthreads();
    for (int s = 128; s > 0; s >>= 1) {
        if (tid < s) red[tid] += red[tid + s];
        __syncthreads();
    }
    if (tid == 0) bpeak[b] = red[0];
}

// ---------------- Kernel 3: final 256 -> scalars ----------------
__global__ __launch_bounds__(256) void k_final(const float* __restrict__ bpeak,
                                               const float* __restrict__ bortho,
                                               float* __restrict__ out) {
    const int tid = threadIdx.x;
    __shared__ float s1[256], s2[256];
    s1[tid] = bpeak[tid];
    s2[tid] = bortho[tid];
    __syncthreads();
    for (int s = 128; s > 0; s >>= 1) {
        if (tid < s) { s1[tid] += s1[tid + s]; s2[tid] += s2[tid + s]; }
        __syncthreads();
    }
    if (tid == 0) {
        float peak = PEAK_LAMBDA * s1[0];
        float ortho = ORTHO_LAMBDA * (s2[0] / (float)(NB * NK * NK));
        out[0] = peak + ortho;
        out[1] = peak;
        out[2] = ortho;
    }
}

extern "C" void kernel_launch(void* const* d_in, const int* in_sizes, int n_in,
                              void* d_out, int out_size, void* d_ws, size_t ws_size,
                              hipStream_t stream) {
    const float* a = (const float*)d_in[0];
    float* out = (float*)d_out;
    float* ws = (float*)d_ws;
    float* gram  = ws;                                   // NB*NC*768 floats
    float* rmax  = gram + (size_t)NB * NC * 768;         // 32768
    int*   ridxp = (int*)(rmax + NB * NC * 32);          // 32768
    float* rlogp = (float*)(ridxp + NB * NC * 32);       // 32768
    float* bpeak = rlogp + NB * NC * 32;                 // 256
    float* bortho = bpeak + NB;                          // 256

    k_main<<<NB * NC, 256, 0, stream>>>(a, gram, rmax, ridxp, rlogp);
    k_fin<<<NB, 256, 0, stream>>>(a, gram, rmax, ridxp, rlogp, bpeak, bortho);
    k_final<<<1, 256, 0, stream>>>(bpeak, bortho, out);
}